// Round 6
// baseline (381.519 us; speedup 1.0000x reference)
//
#include <hip/hip_runtime.h>
#include <math.h>

#define BATCH 16
#define TA 2048
#define TV 1024
#define TT 1536
#define DIM 256
#define FD 512

typedef unsigned short u16;
typedef unsigned int u32;
typedef short bf16x8 __attribute__((ext_vector_type(8)));
typedef float f32x4 __attribute__((ext_vector_type(4)));

__device__ __forceinline__ float bf2f(u16 u) {
  union { u32 i; float f; } v; v.i = ((u32)u) << 16; return v.f;
}
__device__ __forceinline__ u16 f2bf(float f) {
  union { float f; u32 i; } v; v.f = f;
  return (u16)((v.i + 0x7fffu + ((v.i >> 16) & 1u)) >> 16);  // RNE
}
__device__ __forceinline__ float gelu_f(float x) {
  return 0.5f * x * (1.0f + erff(x * 0.70710678118654752440f));
}
// async global->LDS, 16B per lane. LDS dest = wave-uniform base + lane*16.
__device__ __forceinline__ void async16(const u16* g, u16* l) {
  __builtin_amdgcn_global_load_lds((const __attribute__((address_space(1))) void*)g,
                                   (__attribute__((address_space(3))) void*)l, 16, 0, 0);
}

// ---- weight prep: fp32 -> bf16.
// Conv weights permuted to K-ordered async16-ready chunks:
//   W[kk][unit][8] with kk = tap*8 + c0/32, unit = (o>>4)*64 + q*16 + (o&15),
//   elem j: c = (kk&7)*32 + q*8 + j. Chunk kk = 8 KB contiguous.
__global__ __launch_bounds__(256) void k_prep(
    const float* __restrict__ a3w, const float* __restrict__ a5w,
    const float* __restrict__ v3w, const float* __restrict__ v5w,
    const float* __restrict__ pw,
    u16* __restrict__ w3a, u16* __restrict__ w5a,
    u16* __restrict__ w3v, u16* __restrict__ w5v, u16* __restrict__ wp) {
  int idx = blockIdx.x * 256 + threadIdx.x;
  if (idx < 524288) {
    int e, ktaps;
    const float* src;
    u16* dst;
    if (idx < 98304)       { e = idx;          ktaps = 3; src = a3w; dst = w3a; }
    else if (idx < 262144) { e = idx - 98304;  ktaps = 5; src = a5w; dst = w5a; }
    else if (idx < 360448) { e = idx - 262144; ktaps = 3; src = v3w; dst = w3v; }
    else                   { e = idx - 360448; ktaps = 5; src = v5w; dst = w5v; }
    int kk = e >> 12, r = e & 4095;
    int j = r & 7, unit = r >> 3;
    int fb = unit >> 6, rem = unit & 63;
    int q = rem >> 4, colp = rem & 15;
    int o = fb * 16 + colp;
    int tap = kk >> 3;
    int c = (kk & 7) * 32 + q * 8 + j;
    dst[e] = f2bf(src[(o * 256 + c) * ktaps + tap]);
  } else if (idx < 786432) {               // proj [512][512] straight copy
    int t = idx - 524288;
    wp[t] = f2bf(pw[t]);
  }
}

// ---------------- linear interp to T=1536, output bf16 [B][T][256] ----------
__global__ __launch_bounds__(256) void k_interp(const float* __restrict__ in,
                                                u16* __restrict__ out,
                                                int t_in, float scale) {
  int b = blockIdx.y;
  int i = blockIdx.x * 256 + threadIdx.x;   // [0, TT*32)
  int t = i >> 5, dg = i & 31;              // dg: group of 8 dims
  float src = ((float)t + 0.5f) * scale - 0.5f;
  src = fmaxf(src, 0.0f);
  int i0 = (int)floorf(src);
  if (i0 > t_in - 1) i0 = t_in - 1;
  int i1 = i0 + 1; if (i1 > t_in - 1) i1 = t_in - 1;
  float w = src - (float)i0;
  float om = 1.0f - w;
  const float4* p0 = (const float4*)(in + ((size_t)(b * t_in + i0)) * DIM + dg * 8);
  const float4* p1 = (const float4*)(in + ((size_t)(b * t_in + i1)) * DIM + dg * 8);
  float4 x0a = p0[0], x0b = p0[1], x1a = p1[0], x1b = p1[1];
  u16 r[8];
  r[0] = f2bf(x0a.x * om + x1a.x * w); r[1] = f2bf(x0a.y * om + x1a.y * w);
  r[2] = f2bf(x0a.z * om + x1a.z * w); r[3] = f2bf(x0a.w * om + x1a.w * w);
  r[4] = f2bf(x0b.x * om + x1b.x * w); r[5] = f2bf(x0b.y * om + x1b.y * w);
  r[6] = f2bf(x0b.z * om + x1b.z * w); r[7] = f2bf(x0b.w * om + x1b.w * w);
  u32 w0 = (u32)r[0] | ((u32)r[1] << 16), w1 = (u32)r[2] | ((u32)r[3] << 16);
  u32 w2 = (u32)r[4] | ((u32)r[5] << 16), w3 = (u32)r[6] | ((u32)r[7] << 16);
  *(uint4*)(out + ((size_t)(b * TT + t)) * DIM + dg * 8) = make_uint4(w0, w1, w2, w3);
}

// ---------------- zero fp32 accumulators -----------------------------------
__global__ __launch_bounds__(256) void k_zero(float* __restrict__ p, int n) {
  int i = blockIdx.x * 256 + threadIdx.x;
  if (i < n) p[i] = 0.f;
}

// ---------------- conv GEMM, fully unrolled, channel-split -----------------
template <int TAPS>
__global__ __launch_bounds__(256) void k_convN(
    const u16* __restrict__ xa, const u16* __restrict__ xv,
    const u16* __restrict__ Wa, const u16* __restrict__ Wv,
    const float* __restrict__ ba, const float* __restrict__ bv,
    u16* __restrict__ outMa, u16* __restrict__ outMv,
    u16* __restrict__ outTa, u16* __restrict__ outTv,
    float* __restrict__ nsqa, float* __restrict__ nsqv) {
  constexpr int S = TAPS * 8;
  constexpr int OFF = (TAPS == 3) ? 1 : 2;
  constexpr int CHB = (TAPS == 3) ? 0 : 128;
  __shared__ __align__(16) u16 xs[68 * 264];   // input rows t0-2..t0+65; tb overlays
  __shared__ __align__(16) u16 Bs[2 * 4096];   // weight chunk double buffer
  u16* tb = xs;                                // [128][72] transpose buffer (epilogue)
  int b = blockIdx.y, t0 = blockIdx.x * 64;
  int isv = blockIdx.z;
  const u16* xin = isv ? xv : xa;
  const u16* W   = isv ? Wv : Wa;
  const float* bias = isv ? bv : ba;
  u16* outM  = isv ? outMv : outMa;
  u16* outT  = isv ? outTv : outTa;
  float* nsq = isv ? nsqv : nsqa;
  int tid = threadIdx.x, wave = tid >> 6, lane = tid & 63;
  int col = lane & 15, quad = lane >> 4;

  // stage 68 input rows (zeros outside [0,T))
  for (int i = tid; i < 68 * 32; i += 256) {
    int row = i >> 5, un = i & 31;
    int t = t0 + row - 2;
    uint4 val = make_uint4(0, 0, 0, 0);
    if (t >= 0 && t < TT) val = *(const uint4*)(xin + ((size_t)(b * TT + t)) * DIM + un * 8);
    *(uint4*)(xs + row * 264 + un * 8) = val;
  }
  // prefetch chunk 0 into buf 0 (each wave stages 1024 elems = 2 x 16B/lane)
  const u16* Wb = W + wave * 1024 + lane * 8;
  u16* BsW = Bs + wave * 1024;
  async16(Wb, BsW);
  async16(Wb + 512, BsW + 512);

  f32x4 acc[4][2];
  f32x4 zz = {0.f, 0.f, 0.f, 0.f};
#pragma unroll
  for (int rt = 0; rt < 4; rt++) { acc[rt][0] = zz; acc[rt][1] = zz; }

  const u16* afp = xs + (col + 2) * 264 + quad * 8;
  const u16* bfp = Bs + wave * 1024 + quad * 128 + col * 8;

#pragma unroll
  for (int s = 0; s < S; s++) {
    __syncthreads();                 // chunk s staged; prev reads of other buf done
    if (s + 1 < S) {
      const u16* src = Wb + (size_t)(s + 1) * 4096;
      u16* dst = Bs + ((s + 1) & 1) * 4096 + wave * 1024;
      async16(src, dst);
      async16(src + 512, dst + 512);
    }
    int shift = (s >> 3) - OFF;      // compile-time after unroll
    int c0 = (s & 7) * 32;
    bf16x8 af[4];
#pragma unroll
    for (int rt = 0; rt < 4; rt++)
      af[rt] = *(const bf16x8*)(afp + (rt * 16 + shift) * 264 + c0);
    bf16x8 bf0 = *(const bf16x8*)(bfp + (s & 1) * 4096);
    bf16x8 bf1 = *(const bf16x8*)(bfp + (s & 1) * 4096 + 512);
#pragma unroll
    for (int rt = 0; rt < 4; rt++) {
      acc[rt][0] = __builtin_amdgcn_mfma_f32_16x16x32_bf16(af[rt], bf0, acc[rt][0], 0, 0, 0);
      acc[rt][1] = __builtin_amdgcn_mfma_f32_16x16x32_bf16(af[rt], bf1, acc[rt][1], 0, 0, 0);
    }
  }
  __syncthreads();                   // xs reads done; safe to overlay tb

  // epilogue: bias + gelu + per-row sumsq (32 ch of this wave) + tb + outM
  float bia0 = bias[wave * 32 + col];
  float bia1 = bias[wave * 32 + 16 + col];
  float ss[4][4];
#pragma unroll
  for (int rt = 0; rt < 4; rt++)
#pragma unroll
    for (int r = 0; r < 4; r++) ss[rt][r] = 0.f;
#pragma unroll
  for (int rt = 0; rt < 4; rt++)
#pragma unroll
    for (int h = 0; h < 2; h++) {
      float bia = h ? bia1 : bia0;
      int chL = wave * 32 + h * 16 + col;
#pragma unroll
      for (int r = 0; r < 4; r++) {
        float g = gelu_f(acc[rt][h][r] + bia);
        ss[rt][r] += g * g;
        int trow = rt * 16 + quad * 4 + r;
        u16 gb = f2bf(g);
        tb[chL * 72 + trow] = gb;
        outM[((size_t)(b * TT + t0 + trow)) * DIM + CHB + chL] = gb;
      }
    }
#pragma unroll
  for (int rt = 0; rt < 4; rt++)
#pragma unroll
    for (int r = 0; r < 4; r++) {
      float v = ss[rt][r];
      v += __shfl_xor(v, 1, 64); v += __shfl_xor(v, 2, 64);
      v += __shfl_xor(v, 4, 64); v += __shfl_xor(v, 8, 64);
      if (col == 0)
        atomicAdd(&nsq[b * TT + t0 + rt * 16 + quad * 4 + r], v);
    }
  __syncthreads();
  // outT: 2 threads per channel write 32 contiguous t each
  {
    int ch = tid >> 1, half = tid & 1;
    uint4* dst = (uint4*)(outT + ((size_t)(b * 256 + CHB + ch)) * TT + t0 + half * 32);
#pragma unroll
    for (int i = 0; i < 4; i++)
      dst[i] = *(const uint4*)(tb + ch * 72 + half * 32 + i * 8);
  }
}

// ---- sim+exp: E = exp((aM.vM^T)/(|a||v|)), write E and E^T (bf16),
//      accumulate rsum (row sums of E) and csum (col sums) via atomics.
//      sim in [-1,1] => exp is numerically safe without max subtraction.
//      Epilogue is LDS-staged: each wave dumps its 64x64 bf16 tile to a
//      wave-private [64][68] region, then re-reads row-major (E) and
//      col-major (ET) to emit fully-coalesced 16B stores.
__global__ __launch_bounds__(256) void k_sim(const u16* __restrict__ A,
                                             const u16* __restrict__ Bm,
                                             const float* __restrict__ naq,
                                             const float* __restrict__ nvq,
                                             u16* __restrict__ E,
                                             u16* __restrict__ ET,
                                             float* __restrict__ rsum,
                                             float* __restrict__ csum) {
  __shared__ __align__(16) u16 smem[4 * 64 * 68];  // stage; As/Bs overlay front
  __shared__ float sRa[128], sRv[128];
  u16* As = smem;            // 128*32
  u16* Bs = smem + 4096;     // 128*32
  int b = blockIdx.z, m0 = blockIdx.y * 128, n0 = blockIdx.x * 128;
  int tid = threadIdx.x, wave = tid >> 6, lane = tid & 63;
  int col = lane & 15, quad = lane >> 4;
  int wm = (wave >> 1) * 64, wn = (wave & 1) * 64;
  int lrow = lane >> 2, lcol = (lane & 3) * 8;
  if (tid < 128) sRa[tid] = 1.0f / fmaxf(sqrtf(naq[b * TT + m0 + tid]), 1e-12f);
  else sRv[tid - 128] = 1.0f / fmaxf(sqrtf(nvq[b * TT + tid - 128 + n0]), 1e-12f);
  const u16* Ab = A + ((size_t)(b * TT + m0)) * DIM;
  const u16* Bb = Bm + ((size_t)(b * TT + n0)) * DIM;
  f32x4 acc[4][4];
  f32x4 zz = {0.f, 0.f, 0.f, 0.f};
#pragma unroll
  for (int i = 0; i < 4; i++)
#pragma unroll
    for (int j = 0; j < 4; j++) acc[i][j] = zz;

  for (int kt = 0; kt < 8; kt++) {
    int k0 = kt * 32;
    __syncthreads();
#pragma unroll
    for (int i = 0; i < 2; i++) {
      int rb = wave * 32 + i * 16;
      async16(Ab + ((size_t)(rb + lrow)) * DIM + k0 + lcol, As + rb * 32);
      async16(Bb + ((size_t)(rb + lrow)) * DIM + k0 + lcol, Bs + rb * 32);
    }
    __syncthreads();
    bf16x8 af[4], bfr[4];
#pragma unroll
    for (int mt = 0; mt < 4; mt++) af[mt] = *(const bf16x8*)(As + (wm + mt * 16 + col) * 32 + quad * 8);
#pragma unroll
    for (int nt = 0; nt < 4; nt++) bfr[nt] = *(const bf16x8*)(Bs + (wn + nt * 16 + col) * 32 + quad * 8);
#pragma unroll
    for (int mt = 0; mt < 4; mt++)
#pragma unroll
      for (int nt = 0; nt < 4; nt++)
        acc[mt][nt] = __builtin_amdgcn_mfma_f32_16x16x32_bf16(af[mt], bfr[nt], acc[mt][nt], 0, 0, 0);
  }
  __syncthreads();                   // As/Bs reads done; stage overlays them

  // ---- epilogue step 1: exp + sums + scatter into wave-private LDS tile ----
  u16* tw = smem + wave * (64 * 68);
  float rowp[4][4];
#pragma unroll
  for (int mt = 0; mt < 4; mt++)
#pragma unroll
    for (int r = 0; r < 4; r++) rowp[mt][r] = 0.f;

#pragma unroll
  for (int nt = 0; nt < 4; nt++) {
    int cl = wn + nt * 16 + col;
    float rv = sRv[cl];
    float colp = 0.f;
#pragma unroll
    for (int mt = 0; mt < 4; mt++) {
#pragma unroll
      for (int r = 0; r < 4; r++) {
        int rloc = mt * 16 + quad * 4 + r;   // row within wave tile
        float e = __expf(acc[mt][nt][r] * sRa[wm + rloc] * rv);
        rowp[mt][r] += e;
        colp += e;
        tw[rloc * 68 + nt * 16 + col] = f2bf(e);  // 2-way banks (free)
      }
    }
    colp += __shfl_xor(colp, 16, 64);
    colp += __shfl_xor(colp, 32, 64);
    if (quad == 0) atomicAdd(&csum[b * TT + n0 + cl], colp);
  }
#pragma unroll
  for (int mt = 0; mt < 4; mt++)
#pragma unroll
    for (int r = 0; r < 4; r++) {
      float v = rowp[mt][r];
      v += __shfl_xor(v, 1, 64); v += __shfl_xor(v, 2, 64);
      v += __shfl_xor(v, 4, 64); v += __shfl_xor(v, 8, 64);
      if (col == 0) atomicAdd(&rsum[b * TT + m0 + wm + mt * 16 + quad * 4 + r], v);
    }

  // ---- step 2: E stores, row-major, 128B segments (8 lanes x 16B per row) --
  {
    int rl = lane >> 3, seg = lane & 7;     // 8 rows/pass, 8 x 16B segs
#pragma unroll
    for (int p = 0; p < 8; p++) {
      int row = p * 8 + rl;
      uint2 a = *(const uint2*)(tw + row * 68 + seg * 8);
      uint2 c = *(const uint2*)(tw + row * 68 + seg * 8 + 4);
      *(uint4*)(E + ((size_t)(b * TT + m0 + wm + row)) * TT + n0 + wn + seg * 8) =
          make_uint4(a.x, a.y, c.x, c.y);
    }
  }
  // ---- step 3: ET stores, transposed gather, 128B segments -----------------
  {
    int nl = lane >> 3, ms = (lane & 7) * 8;
#pragma unroll
    for (int p = 0; p < 8; p++) {
      int nn = p * 8 + nl;
      u16 g[8];
#pragma unroll
      for (int j = 0; j < 8; j++) g[j] = tw[(ms + j) * 68 + nn];
      u32 w0 = (u32)g[0] | ((u32)g[1] << 16), w1 = (u32)g[2] | ((u32)g[3] << 16);
      u32 w2 = (u32)g[4] | ((u32)g[5] << 16), w3 = (u32)g[6] | ((u32)g[7] << 16);
      *(uint4*)(ET + ((size_t)(b * TT + n0 + wn + nn)) * TT + m0 + wm + ms) =
          make_uint4(w0, w1, w2, w3);
    }
  }
}

// ---------------- PV: fused[...] = itp + (P @ V) / dsum --------------------
// P: [B][T][T] bf16 row-major (E for a_enh, ET for v_enh), k-contiguous.
// Bt: [B][256][T]. Pure m97-style GEMM, 64(m) x 128(n) tile, BK=32.
__global__ __launch_bounds__(256) void k_pv(
    const u16* __restrict__ P, const u16* __restrict__ Bt,
    const float* __restrict__ dsum,
    const u16* __restrict__ itp, u16* __restrict__ fused, int dstoff) {
  __shared__ u16 As[64 * 32];
  __shared__ u16 Bs[128 * 32];
  __shared__ float sSum[64];
  int b = blockIdx.z, m0 = blockIdx.y * 64, n0 = blockIdx.x * 128;
  int tid = threadIdx.x, wave = tid >> 6, lane = tid & 63;
  int col = lane & 15, quad = lane >> 4;
  int wm = (wave >> 1) * 32, wn = (wave & 1) * 64;
  int lrow = lane >> 2, lcol = (lane & 3) * 8;
  if (tid < 64) sSum[tid] = dsum[b * TT + m0 + tid];
  const u16* Ab = P + ((size_t)(b * TT + m0)) * TT;
  const u16* Bb = Bt + ((size_t)(b * 256 + n0)) * TT;
  f32x4 acc[2][4];
  f32x4 zz = {0.f, 0.f, 0.f, 0.f};
#pragma unroll
  for (int i = 0; i < 2; i++)
#pragma unroll
    for (int j = 0; j < 4; j++) acc[i][j] = zz;

  for (int kt = 0; kt < 48; kt++) {
    int k0 = kt * 32;
    __syncthreads();
    async16(Ab + ((size_t)(wave * 16 + lrow)) * TT + k0 + lcol, As + wave * 16 * 32);
#pragma unroll
    for (int i = 0; i < 2; i++) {
      int rb = wave * 32 + i * 16;
      async16(Bb + ((size_t)(rb + lrow)) * TT + k0 + lcol, Bs + rb * 32);
    }
    __syncthreads();
    bf16x8 af[2], bfr[4];
#pragma unroll
    for (int mt = 0; mt < 2; mt++) af[mt] = *(const bf16x8*)(As + (wm + mt * 16 + col) * 32 + quad * 8);
#pragma unroll
    for (int nt = 0; nt < 4; nt++) bfr[nt] = *(const bf16x8*)(Bs + (wn + nt * 16 + col) * 32 + quad * 8);
#pragma unroll
    for (int mt = 0; mt < 2; mt++)
#pragma unroll
      for (int nt = 0; nt < 4; nt++)
        acc[mt][nt] = __builtin_amdgcn_mfma_f32_16x16x32_bf16(af[mt], bfr[nt], acc[mt][nt], 0, 0, 0);
  }
#pragma unroll
  for (int mt = 0; mt < 2; mt++)
#pragma unroll
    for (int nt = 0; nt < 4; nt++)
#pragma unroll
      for (int r = 0; r < 4; r++) {
        int row = wm + mt * 16 + quad * 4 + r;
        int t = m0 + row;
        int d = n0 + wn + nt * 16 + col;
        float val = acc[mt][nt][r] / sSum[row] + bf2f(itp[((size_t)(b * TT + t)) * DIM + d]);
        fused[((size_t)(b * TT + t)) * FD + dstoff + d] = f2bf(val);
      }
}

// ---------------- proj: out = gelu(fused @ Wp^T + b), fp32 out -------------
__global__ __launch_bounds__(256) void k_proj(const u16* __restrict__ Am,
                                              const u16* __restrict__ Bw,
                                              const float* __restrict__ bias,
                                              float* __restrict__ out) {
  __shared__ u16 As[128 * 32], Bs[128 * 32];
  int m0 = blockIdx.y * 128, n0 = blockIdx.x * 128;
  int tid = threadIdx.x, wave = tid >> 6, lane = tid & 63;
  int col = lane & 15, quad = lane >> 4;
  int wm = (wave >> 1) * 64, wn = (wave & 1) * 64;
  int lrow = lane >> 2, lcol = (lane & 3) * 8;
  const u16* Ab = Am + (size_t)m0 * FD;
  const u16* Bb = Bw + (size_t)n0 * FD;
  f32x4 acc[4][4];
  f32x4 zz = {0.f, 0.f, 0.f, 0.f};
#pragma unroll
  for (int i = 0; i < 4; i++)
#pragma unroll
    for (int j = 0; j < 4; j++) acc[i][j] = zz;

  for (int kt = 0; kt < 16; kt++) {
    int k0 = kt * 32;
    __syncthreads();
#pragma unroll
    for (int i = 0; i < 2; i++) {
      int rb = wave * 32 + i * 16;
      async16(Ab + ((size_t)(rb + lrow)) * FD + k0 + lcol, As + rb * 32);
      async16(Bb + ((size_t)(rb + lrow)) * FD + k0 + lcol, Bs + rb * 32);
    }
    __syncthreads();
    bf16x8 af[4], bfr[4];
#pragma unroll
    for (int mt = 0; mt < 4; mt++) af[mt] = *(const bf16x8*)(As + (wm + mt * 16 + col) * 32 + quad * 8);
#pragma unroll
    for (int nt = 0; nt < 4; nt++) bfr[nt] = *(const bf16x8*)(Bs + (wn + nt * 16 + col) * 32 + quad * 8);
#pragma unroll
    for (int mt = 0; mt < 4; mt++)
#pragma unroll
      for (int nt = 0; nt < 4; nt++)
        acc[mt][nt] = __builtin_amdgcn_mfma_f32_16x16x32_bf16(af[mt], bfr[nt], acc[mt][nt], 0, 0, 0);
  }
#pragma unroll
  for (int nt = 0; nt < 4; nt++) {
    float bia = bias[n0 + wn + nt * 16 + col];
#pragma unroll
    for (int mt = 0; mt < 4; mt++)
#pragma unroll
      for (int r = 0; r < 4; r++) {
        int row = m0 + wm + mt * 16 + quad * 4 + r;
        int cc = n0 + wn + nt * 16 + col;
        out[(size_t)row * FD + cc] = gelu_f(acc[mt][nt][r] + bia);
      }
  }
}

extern "C" void kernel_launch(void* const* d_in, const int* in_sizes, int n_in,
                              void* d_out, int out_size, void* d_ws, size_t ws_size,
                              hipStream_t stream) {
  const float* audio = (const float*)d_in[0];
  const float* video = (const float*)d_in[1];
  const float* a3w = (const float*)d_in[2];
  const float* a3b = (const float*)d_in[3];
  const float* a5w = (const float*)d_in[4];
  const float* a5b = (const float*)d_in[5];
  const float* v3w = (const float*)d_in[6];
  const float* v3b = (const float*)d_in[7];
  const float* v5w = (const float*)d_in[8];
  const float* v5b = (const float*)d_in[9];
  const float* pw  = (const float*)d_in[10];
  const float* pb  = (const float*)d_in[11];
  float* out = (float*)d_out;

  char* ws = (char*)d_ws;
  size_t off = 0;
  auto alloc = [&](size_t bytes) {
    char* p = ws + off;
    off += (bytes + 255) & ~(size_t)255;
    return p;
  };
  size_t szItp = (size_t)BATCH * TT * DIM * 2;
  u16* a_itp = (u16*)alloc(szItp);
  u16* v_itp = (u16*)alloc(szItp);
  u16* aM  = (u16*)alloc(szItp);
  u16* vM  = (u16*)alloc(szItp);
  u16* aMT = (u16*)alloc(szItp);
  u16* vMT = (u16*)alloc(szItp);
  u16* E   = (u16*)alloc((size_t)BATCH * TT * TT * 2);
  u16* ET  = (u16*)alloc((size_t)BATCH * TT * TT * 2);
  // NOTE: naq/nvq/rsum/csum must stay adjacent (one k_zero covers all four;
  // each is 16*1536*4 = 98304 B, a multiple of the 256 B alloc granule).
  float* naq = (float*)alloc((size_t)BATCH * TT * 4);
  float* nvq = (float*)alloc((size_t)BATCH * TT * 4);
  float* rsum = (float*)alloc((size_t)BATCH * TT * 4);
  float* csum = (float*)alloc((size_t)BATCH * TT * 4);
  u16* fusedb = (u16*)alloc((size_t)BATCH * TT * FD * 2);
  u16* w3a = (u16*)alloc(3 * 128 * 256 * 2);
  u16* w5a = (u16*)alloc(5 * 128 * 256 * 2);
  u16* w3v = (u16*)alloc(3 * 128 * 256 * 2);
  u16* w5v = (u16*)alloc(5 * 128 * 256 * 2);
  u16* wp  = (u16*)alloc(512 * 512 * 2);

  k_prep<<<3072, 256, 0, stream>>>(a3w, a5w, v3w, v5w, pw, w3a, w5a, w3v, w5v, wp);
  k_interp<<<dim3(192, 16), 256, 0, stream>>>(audio, a_itp, TA, (float)((double)TA / TT));
  k_interp<<<dim3(192, 16), 256, 0, stream>>>(video, v_itp, TV, (float)((double)TV / TT));
  k_zero<<<384, 256, 0, stream>>>(naq, 4 * BATCH * TT);
  k_convN<3><<<dim3(24, 16, 2), 256, 0, stream>>>(a_itp, v_itp, w3a, w3v, a3b, v3b,
                                                  aM, vM, aMT, vMT, naq, nvq);
  k_convN<5><<<dim3(24, 16, 2), 256, 0, stream>>>(a_itp, v_itp, w5a, w5v, a5b, v5b,
                                                  aM, vM, aMT, vMT, naq, nvq);
  k_sim<<<dim3(12, 12, 16), 256, 0, stream>>>(aM, vM, naq, nvq, E, ET, rsum, csum);
  k_pv<<<dim3(2, 24, 16), 256, 0, stream>>>(E, vMT, rsum, a_itp, fusedb, 0);
  k_pv<<<dim3(2, 24, 16), 256, 0, stream>>>(ET, aMT, csum, v_itp, fusedb, 256);
  k_proj<<<dim3(4, 192), 256, 0, stream>>>(fusedb, wp, pb, out);
}